// Round 15
// baseline (456.671 us; speedup 1.0000x reference)
//
#include <hip/hip_runtime.h>
#include <cstdint>
#include <cstddef>

// GIN 3-layer + BN + mean-pool. R15 = R14 (fp16, 1-plane W) with:
//  - BM=64 GEMM (4 blocks/CU via launch_bounds(256,4), grid 782 -> better
//    latency hiding + finer tail; structure = R11's validated phase-1)
//  - prep_k fusing x->fp16, W conversion, deg/stats zeroing (21->16 dispatches)

constexpr int N_NODES  = 50000;
constexpr int N_EDGES  = 800000;
constexpr int F_IN     = 128;
constexpr int HID      = 256;
constexpr int N_GRAPHS = 512;
constexpr float BN_EPS = 1e-5f;

constexpr int SCAN_CHUNK = 4096;
constexpr int SCAN_NB    = (N_NODES + SCAN_CHUNK - 1) / SCAN_CHUNK; // 13

typedef unsigned short u16;
typedef u16 u16x2 __attribute__((ext_vector_type(2)));
typedef u16 u16x4 __attribute__((ext_vector_type(4)));
typedef u16 u16x8 __attribute__((ext_vector_type(8)));
typedef _Float16 f16;
typedef f16 f16x8 __attribute__((ext_vector_type(8)));
typedef float f32x4 __attribute__((ext_vector_type(4)));

__device__ __forceinline__ u16 f2h(float f) {
    _Float16 h = (_Float16)f;
    return __builtin_bit_cast(u16, h);
}
__device__ __forceinline__ float h2f(u16 h) {
    return (float)__builtin_bit_cast(_Float16, h);
}

// async global->LDS, 16B per lane; LDS dest = wave-uniform base (+lane*16 HW),
// global source = PER-LANE address.
__device__ __forceinline__ void gload16(const void* g, void* l) {
    __builtin_amdgcn_global_load_lds(
        (const __attribute__((address_space(1))) uint32_t*)g,
        (__attribute__((address_space(3))) uint32_t*)l, 16, 0, 0);
}

// ---- fused prep: x->fp16, W->fp16 pre-swizzled image, zero deg & stats ----
__global__ void prep_k(const float* __restrict__ x, u16* __restrict__ Xb,
                       const float* __restrict__ w1a, const float* __restrict__ w2a,
                       const float* __restrict__ w1s, const float* __restrict__ w2s,
                       u16* __restrict__ th, int* __restrict__ deg,
                       float* __restrict__ stats) {
    int idx = blockIdx.x * 256 + threadIdx.x;   // grid 3125*256 = 800000
    // x -> fp16 (8 floats per thread)
    {
        float4 a = reinterpret_cast<const float4*>(x)[idx * 2];
        float4 b = reinterpret_cast<const float4*>(x)[idx * 2 + 1];
        u16x8 v;
        v[0] = f2h(a.x); v[1] = f2h(a.y); v[2] = f2h(a.z); v[3] = f2h(a.w);
        v[4] = f2h(b.x); v[5] = f2h(b.y); v[6] = f2h(b.z); v[7] = f2h(b.w);
        reinterpret_cast<u16x8*>(Xb)[idx] = v;
    }
    // W -> fp16 pre-swizzled LDS image (tile t: [256 n][4 uo][8 e], uo = j^((n>>1)&3))
    if (idx < 360448) {
        const float* W; int local; size_t dof;
        if (idx < 32768)       { W = w1a;         local = idx;          dof = 0; }
        else if (idx < 98304)  { W = w2a;         local = idx - 32768;  dof = 32768; }
        else if (idx < 163840) { W = w1s;         local = idx - 98304;  dof = 98304; }
        else if (idx < 229376) { W = w1s + 65536; local = idx - 163840; dof = 163840; }
        else if (idx < 294912) { W = w2s;         local = idx - 229376; dof = 229376; }
        else                   { W = w2s + 65536; local = idx - 294912; dof = 294912; }
        int n = local & 255, k = local >> 8;
        float f = W[(size_t)k * 256 + n];
        int t = k >> 5, j = (k >> 3) & 3, e = k & 7;
        int uo = j ^ ((n >> 1) & 3);
        th[dof + (size_t)t * 8192 + n * 32 + uo * 8 + e] = f2h(f);
    }
    if (idx < N_NODES) deg[idx] = 0;
    if (idx < 1536) stats[idx] = 0.f;
}

// ---------------- CSR build ----------------
__global__ void hist_k(const int* __restrict__ dst, int* __restrict__ deg) {
    int e = blockIdx.x * 256 + threadIdx.x;
    if (e < N_EDGES) atomicAdd(&deg[dst[e]], 1);
}

__global__ void scan_part1(const int* __restrict__ in, int* __restrict__ bsum) {
    __shared__ int sm[256];
    int t = threadIdx.x;
    int base = blockIdx.x * SCAN_CHUNK + t * 16;
    int s = 0;
#pragma unroll
    for (int j = 0; j < 16; j++) { int idx = base + j; s += (idx < N_NODES) ? in[idx] : 0; }
    sm[t] = s; __syncthreads();
    for (int off = 128; off > 0; off >>= 1) {
        if (t < off) sm[t] += sm[t + off];
        __syncthreads();
    }
    if (t == 0) bsum[blockIdx.x] = sm[0];
}

__global__ void scan_tops(int* __restrict__ bsum, int* __restrict__ rowptr) {
    if (threadIdx.x == 0 && blockIdx.x == 0) {
        int acc = 0;
        for (int i = 0; i < SCAN_NB; i++) { int v = bsum[i]; bsum[i] = acc; acc += v; }
        rowptr[N_NODES] = acc; // == N_EDGES
    }
}

__global__ void scan_final(const int* __restrict__ in, const int* __restrict__ bsum,
                           int* __restrict__ rowptr, int* __restrict__ cursor) {
    __shared__ int sm[256];
    int t = threadIdx.x;
    int base = blockIdx.x * SCAN_CHUNK + t * 16;
    int loc[16]; int s = 0;
#pragma unroll
    for (int j = 0; j < 16; j++) { int idx = base + j; loc[j] = s; s += (idx < N_NODES) ? in[idx] : 0; }
    sm[t] = s; __syncthreads();
    for (int off = 1; off < 256; off <<= 1) {
        int v = (t >= off) ? sm[t - off] : 0;
        __syncthreads();
        sm[t] += v;
        __syncthreads();
    }
    int excl = sm[t] - s + bsum[blockIdx.x];
#pragma unroll
    for (int j = 0; j < 16; j++) {
        int idx = base + j;
        if (idx < N_NODES) { int rp = excl + loc[j]; rowptr[idx] = rp; cursor[idx] = rp; }
    }
}

__global__ void build_csr(const int* __restrict__ src, const int* __restrict__ dst,
                          int* __restrict__ cursor, int* __restrict__ col) {
    int e = blockIdx.x * 256 + threadIdx.x;
    if (e < N_EDGES) {
        int d = dst[e];
        int p = atomicAdd(&cursor[d], 1);
        col[p] = src[e];
    }
}

// -------- aggregation (fp16 in/out, fp32 accum), BN fold computed inline --------
template <int F, bool FOLD>
__global__ __launch_bounds__(256) void aggregate_k(const u16* __restrict__ h,
                                                   const int* __restrict__ rowptr,
                                                   const int* __restrict__ col,
                                                   const float* __restrict__ stats,
                                                   const float* __restrict__ gamma,
                                                   const float* __restrict__ beta,
                                                   u16* __restrict__ outp) {
    int node = blockIdx.x * 4 + (threadIdx.x >> 6);
    if (node >= N_NODES) return;
    int lane = threadIdx.x & 63;
    int beg = rowptr[node], end = rowptr[node + 1];
    if constexpr (F == 256) {
        float sc[4], sh[4];
        if constexpr (FOLD) {
            int c4 = lane * 4;
#pragma unroll
            for (int i = 0; i < 4; i++) {
                float mu  = stats[c4 + i] * (1.f / N_NODES);
                float var = stats[HID + c4 + i] * (1.f / N_NODES) - mu * mu;
                float g = gamma[c4 + i] * rsqrtf(var + BN_EPS);
                sc[i] = g;
                sh[i] = beta[c4 + i] - mu * g;
            }
        }
        const u16x4* hp = reinterpret_cast<const u16x4*>(h); // row stride 64
        u16x4 sv = hp[(size_t)node * 64 + lane];
        float acc[4] = {h2f(sv[0]), h2f(sv[1]), h2f(sv[2]), h2f(sv[3])};
        int e = beg;
        for (; e + 4 <= end; e += 4) {
            int s0 = col[e], s1 = col[e + 1], s2 = col[e + 2], s3 = col[e + 3];
            u16x4 v0 = hp[(size_t)s0 * 64 + lane];
            u16x4 v1 = hp[(size_t)s1 * 64 + lane];
            u16x4 v2 = hp[(size_t)s2 * 64 + lane];
            u16x4 v3 = hp[(size_t)s3 * 64 + lane];
#pragma unroll
            for (int i = 0; i < 4; i++)
                acc[i] += (h2f(v0[i]) + h2f(v1[i])) + (h2f(v2[i]) + h2f(v3[i]));
        }
        for (; e < end; ++e) {
            int s = col[e];
            u16x4 v = hp[(size_t)s * 64 + lane];
#pragma unroll
            for (int i = 0; i < 4; i++) acc[i] += h2f(v[i]);
        }
        if constexpr (FOLD) {
            float m = (float)(end - beg + 1);
#pragma unroll
            for (int i = 0; i < 4; i++) acc[i] = acc[i] * sc[i] + m * sh[i];
        }
        u16x4 r;
#pragma unroll
        for (int i = 0; i < 4; i++) r[i] = f2h(acc[i]);
        reinterpret_cast<u16x4*>(outp)[(size_t)node * 64 + lane] = r;
    } else { // F == 128, no fold (layer-1 input)
        const u16x2* hp = reinterpret_cast<const u16x2*>(h); // row stride 64
        u16x2 sv = hp[(size_t)node * 64 + lane];
        float acc[2] = {h2f(sv[0]), h2f(sv[1])};
        int e = beg;
        for (; e + 4 <= end; e += 4) {
            int s0 = col[e], s1 = col[e + 1], s2 = col[e + 2], s3 = col[e + 3];
            u16x2 v0 = hp[(size_t)s0 * 64 + lane];
            u16x2 v1 = hp[(size_t)s1 * 64 + lane];
            u16x2 v2 = hp[(size_t)s2 * 64 + lane];
            u16x2 v3 = hp[(size_t)s3 * 64 + lane];
#pragma unroll
            for (int i = 0; i < 2; i++)
                acc[i] += (h2f(v0[i]) + h2f(v1[i])) + (h2f(v2[i]) + h2f(v3[i]));
        }
        for (; e < end; ++e) {
            int s = col[e];
            u16x2 v = hp[(size_t)s * 64 + lane];
#pragma unroll
            for (int i = 0; i < 2; i++) acc[i] += h2f(v[i]);
        }
        u16x2 r;
        r[0] = f2h(acc[0]); r[1] = f2h(acc[1]);
        reinterpret_cast<u16x2*>(outp)[(size_t)node * 64 + lane] = r;
    }
}

// ------- MFMA GEMM (BM=64): C[M][256] = fp16(relu(A[M][K] @ W + bias)) -------
// 4 waves, wave tile 64x64 (wn = wv). 16 MFMA/K-step. 22.5 KB LDS ->
// 4 blocks/CU via launch_bounds(256,4). In-place safe when strides match.
template <int K, bool STATS>
__global__ __launch_bounds__(256, 4) void gemm_mfma(const u16* __restrict__ A,
                                                    const u16* __restrict__ Wth,
                                                    const float* __restrict__ bias,
                                                    u16* __restrict__ C,
                                                    float* __restrict__ stats) {
    constexpr int BM = 64, BK = 32;
    __shared__ alignas(16) u16 Ah[BM * BK];     // 4 KB
    __shared__ alignas(16) u16 Bh[HID * BK];    // 16 KB
    __shared__ float smsum[HID];
    __shared__ float smsq[HID];

    const int tid  = threadIdx.x;
    const int r0   = blockIdx.x * BM;
    const int lane = tid & 63, wv = tid >> 6;
    const int wn = wv;
    const int l15 = lane & 15, kg = lane >> 4;

    // A staging source precompute (1 KB chunk per wave): nu = wv*64 + lane
    int aro, aco;
    {
        int nu = wv * 64 + lane;
        int r = nu >> 2, us = nu & 3;
        int u = us ^ ((r >> 1) & 3);
        aro = r;
        aco = u * 8;
    }

    f32x4 acc[4][4];
#pragma unroll
    for (int i = 0; i < 4; i++)
#pragma unroll
        for (int j = 0; j < 4; j++) acc[i][j] = (f32x4){0.f, 0.f, 0.f, 0.f};

    for (int k0 = 0; k0 < K; k0 += BK) {
        int t = k0 >> 5;
        // ---- stage A (4 KB): per-lane pre-swizzled source, linear LDS dest ----
        gload16(A + (size_t)(r0 + aro) * K + k0 + aco, (char*)Ah + (size_t)wv * 1024);
        // ---- stage W (16 KB): linear image copy, per-lane source ----
        const char* wh = (const char*)Wth + (size_t)t * 16384 + (size_t)wv * 4096 + (size_t)lane * 16;
#pragma unroll
        for (int c = 0; c < 4; c++)
            gload16(wh + c * 1024, (char*)Bh + (size_t)wv * 4096 + c * 1024);
        __syncthreads();
        // ---- MFMA: wave tile 64x64, 16 mfma per K-step ----
        f16x8 ah[4];
#pragma unroll
        for (int mi = 0; mi < 4; mi++) {
            int r = mi * 16 + l15;
            int off = r * 64 + ((kg ^ ((r >> 1) & 3)) << 4);
            ah[mi] = __builtin_bit_cast(f16x8, *reinterpret_cast<const u16x8*>((const char*)Ah + off));
        }
#pragma unroll
        for (int ni = 0; ni < 4; ni++) {
            int n = wn * 64 + ni * 16 + l15;
            int off = n * 64 + ((kg ^ ((n >> 1) & 3)) << 4);
            f16x8 bh = __builtin_bit_cast(f16x8, *reinterpret_cast<const u16x8*>((const char*)Bh + off));
#pragma unroll
            for (int mi = 0; mi < 4; mi++)
                acc[mi][ni] = __builtin_amdgcn_mfma_f32_16x16x32_f16(ah[mi], bh, acc[mi][ni], 0, 0, 0);
        }
        __syncthreads();
    }
    // ---- epilogue: bias + relu + fp16 store; optional per-column stats ----
    if constexpr (STATS) {
        smsum[tid] = 0.f;
        smsq[tid]  = 0.f;
        __syncthreads();
    }
    float bv[4];
#pragma unroll
    for (int ni = 0; ni < 4; ni++) bv[ni] = bias[wn * 64 + ni * 16 + l15];
    float ps[4] = {}, pq[4] = {};
#pragma unroll
    for (int mi = 0; mi < 4; mi++) {
        int rowb = r0 + mi * 16 + kg * 4;
#pragma unroll
        for (int rr = 0; rr < 4; rr++) {
            int row = rowb + rr;
            if (row < N_NODES) {
                u16* cp = C + (size_t)row * HID + wn * 64 + l15;
#pragma unroll
                for (int ni = 0; ni < 4; ni++) {
                    float v = fmaxf(acc[mi][ni][rr] + bv[ni], 0.f);
                    cp[ni * 16] = f2h(v);
                    if constexpr (STATS) { ps[ni] += v; pq[ni] += v * v; }
                }
            }
        }
    }
    if constexpr (STATS) {
#pragma unroll
        for (int ni = 0; ni < 4; ni++) {
            int c = wn * 64 + ni * 16 + l15;
            atomicAdd(&smsum[c], ps[ni]);
            atomicAdd(&smsq[c], pq[ni]);
        }
        __syncthreads();
        atomicAdd(&stats[tid], smsum[tid]);
        atomicAdd(&stats[HID + tid], smsq[tid]);
    }
}

// ---------------- mean pool (batch sorted), layer-3 BN computed inline ----------------
__device__ __forceinline__ int lowerb(const int* a, int key) {
    int lo = 0, hi = N_NODES;
    while (lo < hi) { int mid = (lo + hi) >> 1; if (a[mid] < key) lo = mid + 1; else hi = mid; }
    return lo;
}

__global__ void pool_k(const u16* __restrict__ h, const int* __restrict__ batch,
                       const float* __restrict__ stats, const float* __restrict__ gamma,
                       const float* __restrict__ beta, float* __restrict__ out) {
    __shared__ int bnd[2];
    int g = blockIdx.x;
    if (threadIdx.x == 0) bnd[0] = lowerb(batch, g);
    if (threadIdx.x == 1) bnd[1] = lowerb(batch, g + 1);
    __syncthreads();
    int lo = bnd[0], hi = bnd[1];
    int c = threadIdx.x;
    float mu  = stats[c] * (1.f / N_NODES);
    float var = stats[HID + c] * (1.f / N_NODES) - mu * mu;
    float sc = gamma[c] * rsqrtf(var + BN_EPS);
    float sh = beta[c] - mu * sc;
    float s = 0.f;
    for (int r = lo; r < hi; ++r) s += h2f(h[(size_t)r * HID + c]);
    int cnt = hi - lo;
    float v = (cnt > 0) ? (sc * (s / (float)cnt) + sh) : 0.f;
    out[(size_t)g * HID + c] = v;
}

// ---------------- launch ----------------
extern "C" void kernel_launch(void* const* d_in, const int* in_sizes, int n_in,
                              void* d_out, int out_size, void* d_ws, size_t ws_size,
                              hipStream_t stream) {
    const float* x   = (const float*)d_in[0];
    const int*   ei  = (const int*)d_in[1];
    const int* batch = (const int*)d_in[2];
    const float* w1a = (const float*)d_in[3];
    const float* b1a = (const float*)d_in[4];
    const float* w2a = (const float*)d_in[5];
    const float* b2a = (const float*)d_in[6];
    const float* ga  = (const float*)d_in[7];
    const float* ba  = (const float*)d_in[8];
    const float* w1s = (const float*)d_in[9];
    const float* b1s = (const float*)d_in[10];
    const float* w2s = (const float*)d_in[11];
    const float* b2s = (const float*)d_in[12];
    const float* gs  = (const float*)d_in[13];
    const float* bs  = (const float*)d_in[14];
    const int* src = ei;
    const int* dst = ei + N_EDGES;

    char* ws = (char*)d_ws;
    size_t off = 0;
    auto alloc = [&](size_t bytes) { void* p = ws + off; off += (bytes + 255) & ~(size_t)255; return p; };
    u16* A      = (u16*)alloc(sizeof(u16) * (size_t)N_NODES * HID);
    u16* B      = (u16*)alloc(sizeof(u16) * (size_t)N_NODES * HID);
    u16* Xb     = (u16*)alloc(sizeof(u16) * (size_t)N_NODES * F_IN);
    int* rowptr = (int*)alloc(sizeof(int) * (N_NODES + 1));
    int* deg    = (int*)alloc(sizeof(int) * N_NODES);
    int* cursor = (int*)alloc(sizeof(int) * N_NODES);
    int* col    = (int*)alloc(sizeof(int) * N_EDGES);
    int* bsum   = (int*)alloc(sizeof(int) * 64);
    float* stats  = (float*)alloc(sizeof(float) * 512 * 3);  // sum||sq per layer
    constexpr size_t WT_TOT = 32768 + 5 * 65536;
    u16* WtH = (u16*)alloc(sizeof(u16) * WT_TOT);
    constexpr size_t o1a = 0, o2a = 32768, o1s0 = 98304, o1s1 = 163840, o2s0 = 229376, o2s1 = 294912;
    float* out    = (float*)d_out;
    (void)ws_size; (void)in_sizes; (void)n_in; (void)out_size;

    // ---- fused prep (x->fp16, W image, zero deg/stats) ----
    prep_k<<<(N_NODES * F_IN / 8 + 255) / 256, 256, 0, stream>>>(
        x, Xb, w1a, w2a, w1s, w2s, WtH, deg, stats);

    // ---- CSR build (by dst) ----
    hist_k<<<N_EDGES / 256, 256, 0, stream>>>(dst, deg);
    scan_part1<<<SCAN_NB, 256, 0, stream>>>(deg, bsum);
    scan_tops<<<1, 64, 0, stream>>>(bsum, rowptr);
    scan_final<<<SCAN_NB, 256, 0, stream>>>(deg, bsum, rowptr, cursor);
    build_csr<<<N_EDGES / 256, 256, 0, stream>>>(src, dst, cursor, col);

    const int AGG_GRID  = (N_NODES + 3) / 4;    // 12500
    const int GEMM_GRID = (N_NODES + 63) / 64;  // 782

    // ---- layer 1 ----
    aggregate_k<128, false><<<AGG_GRID, 256, 0, stream>>>(Xb, rowptr, col, nullptr, nullptr, nullptr, A);
    gemm_mfma<128, false><<<GEMM_GRID, 256, 0, stream>>>(A, WtH + o1a, b1a, B, nullptr);
    gemm_mfma<256, true><<<GEMM_GRID, 256, 0, stream>>>(B, WtH + o2a, b2a, B, stats);

    // ---- layer 2 (BN1 folded into aggregate, scale/shift inline) ----
    aggregate_k<256, true><<<AGG_GRID, 256, 0, stream>>>(B, rowptr, col, stats, ga, ba, A);
    gemm_mfma<256, false><<<GEMM_GRID, 256, 0, stream>>>(A, WtH + o1s0, b1s, A, nullptr);
    gemm_mfma<256, true><<<GEMM_GRID, 256, 0, stream>>>(A, WtH + o2s0, b2s, A, stats + 512);

    // ---- layer 3 (BN2 folded into aggregate) ----
    aggregate_k<256, true><<<AGG_GRID, 256, 0, stream>>>(A, rowptr, col, stats + 512, gs, bs, B);
    gemm_mfma<256, false><<<GEMM_GRID, 256, 0, stream>>>(B, WtH + o1s1, b1s + 256, B, nullptr);
    gemm_mfma<256, true><<<GEMM_GRID, 256, 0, stream>>>(B, WtH + o2s1, b2s + 256, B, stats + 1024);

    // ---- pool (BN3 inline) ----
    pool_k<<<N_GRAPHS, 256, 0, stream>>>(B, batch, stats + 1024, gs + 256, bs + 256, out);
}

// Round 16
// 440.202 us; speedup vs baseline: 1.0374x; 1.0374x over previous
//
#include <hip/hip_runtime.h>
#include <cstdint>
#include <cstddef>

// GIN 3-layer + BN + mean-pool. R16 = R14 (best GEMM: BM=128, fp16, 1-plane W)
// + R15's fused prep_k (x->fp16, W image, deg/stats zeroing in one dispatch).

constexpr int N_NODES  = 50000;
constexpr int N_EDGES  = 800000;
constexpr int F_IN     = 128;
constexpr int HID      = 256;
constexpr int N_GRAPHS = 512;
constexpr float BN_EPS = 1e-5f;

constexpr int SCAN_CHUNK = 4096;
constexpr int SCAN_NB    = (N_NODES + SCAN_CHUNK - 1) / SCAN_CHUNK; // 13

typedef unsigned short u16;
typedef u16 u16x2 __attribute__((ext_vector_type(2)));
typedef u16 u16x4 __attribute__((ext_vector_type(4)));
typedef u16 u16x8 __attribute__((ext_vector_type(8)));
typedef _Float16 f16;
typedef f16 f16x8 __attribute__((ext_vector_type(8)));
typedef float f32x4 __attribute__((ext_vector_type(4)));

__device__ __forceinline__ u16 f2h(float f) {
    _Float16 h = (_Float16)f;
    return __builtin_bit_cast(u16, h);
}
__device__ __forceinline__ float h2f(u16 h) {
    return (float)__builtin_bit_cast(_Float16, h);
}

// async global->LDS, 16B per lane; LDS dest = wave-uniform base (+lane*16 HW),
// global source = PER-LANE address.
__device__ __forceinline__ void gload16(const void* g, void* l) {
    __builtin_amdgcn_global_load_lds(
        (const __attribute__((address_space(1))) uint32_t*)g,
        (__attribute__((address_space(3))) uint32_t*)l, 16, 0, 0);
}

// ---- fused prep: x->fp16, W->fp16 pre-swizzled image, zero deg & stats ----
__global__ void prep_k(const float* __restrict__ x, u16* __restrict__ Xb,
                       const float* __restrict__ w1a, const float* __restrict__ w2a,
                       const float* __restrict__ w1s, const float* __restrict__ w2s,
                       u16* __restrict__ th, int* __restrict__ deg,
                       float* __restrict__ stats) {
    int idx = blockIdx.x * 256 + threadIdx.x;   // grid 3125*256 = 800000
    // x -> fp16 (8 floats per thread)
    {
        float4 a = reinterpret_cast<const float4*>(x)[idx * 2];
        float4 b = reinterpret_cast<const float4*>(x)[idx * 2 + 1];
        u16x8 v;
        v[0] = f2h(a.x); v[1] = f2h(a.y); v[2] = f2h(a.z); v[3] = f2h(a.w);
        v[4] = f2h(b.x); v[5] = f2h(b.y); v[6] = f2h(b.z); v[7] = f2h(b.w);
        reinterpret_cast<u16x8*>(Xb)[idx] = v;
    }
    // W -> fp16 pre-swizzled LDS image (tile t: [256 n][4 uo][8 e], uo = j^((n>>1)&3))
    if (idx < 360448) {
        const float* W; int local; size_t dof;
        if (idx < 32768)       { W = w1a;         local = idx;          dof = 0; }
        else if (idx < 98304)  { W = w2a;         local = idx - 32768;  dof = 32768; }
        else if (idx < 163840) { W = w1s;         local = idx - 98304;  dof = 98304; }
        else if (idx < 229376) { W = w1s + 65536; local = idx - 163840; dof = 163840; }
        else if (idx < 294912) { W = w2s;         local = idx - 229376; dof = 229376; }
        else                   { W = w2s + 65536; local = idx - 294912; dof = 294912; }
        int n = local & 255, k = local >> 8;
        float f = W[(size_t)k * 256 + n];
        int t = k >> 5, j = (k >> 3) & 3, e = k & 7;
        int uo = j ^ ((n >> 1) & 3);
        th[dof + (size_t)t * 8192 + n * 32 + uo * 8 + e] = f2h(f);
    }
    if (idx < N_NODES) deg[idx] = 0;
    if (idx < 1536) stats[idx] = 0.f;
}

// ---------------- CSR build ----------------
__global__ void hist_k(const int* __restrict__ dst, int* __restrict__ deg) {
    int e = blockIdx.x * 256 + threadIdx.x;
    if (e < N_EDGES) atomicAdd(&deg[dst[e]], 1);
}

__global__ void scan_part1(const int* __restrict__ in, int* __restrict__ bsum) {
    __shared__ int sm[256];
    int t = threadIdx.x;
    int base = blockIdx.x * SCAN_CHUNK + t * 16;
    int s = 0;
#pragma unroll
    for (int j = 0; j < 16; j++) { int idx = base + j; s += (idx < N_NODES) ? in[idx] : 0; }
    sm[t] = s; __syncthreads();
    for (int off = 128; off > 0; off >>= 1) {
        if (t < off) sm[t] += sm[t + off];
        __syncthreads();
    }
    if (t == 0) bsum[blockIdx.x] = sm[0];
}

__global__ void scan_tops(int* __restrict__ bsum, int* __restrict__ rowptr) {
    if (threadIdx.x == 0 && blockIdx.x == 0) {
        int acc = 0;
        for (int i = 0; i < SCAN_NB; i++) { int v = bsum[i]; bsum[i] = acc; acc += v; }
        rowptr[N_NODES] = acc; // == N_EDGES
    }
}

__global__ void scan_final(const int* __restrict__ in, const int* __restrict__ bsum,
                           int* __restrict__ rowptr, int* __restrict__ cursor) {
    __shared__ int sm[256];
    int t = threadIdx.x;
    int base = blockIdx.x * SCAN_CHUNK + t * 16;
    int loc[16]; int s = 0;
#pragma unroll
    for (int j = 0; j < 16; j++) { int idx = base + j; loc[j] = s; s += (idx < N_NODES) ? in[idx] : 0; }
    sm[t] = s; __syncthreads();
    for (int off = 1; off < 256; off <<= 1) {
        int v = (t >= off) ? sm[t - off] : 0;
        __syncthreads();
        sm[t] += v;
        __syncthreads();
    }
    int excl = sm[t] - s + bsum[blockIdx.x];
#pragma unroll
    for (int j = 0; j < 16; j++) {
        int idx = base + j;
        if (idx < N_NODES) { int rp = excl + loc[j]; rowptr[idx] = rp; cursor[idx] = rp; }
    }
}

__global__ void build_csr(const int* __restrict__ src, const int* __restrict__ dst,
                          int* __restrict__ cursor, int* __restrict__ col) {
    int e = blockIdx.x * 256 + threadIdx.x;
    if (e < N_EDGES) {
        int d = dst[e];
        int p = atomicAdd(&cursor[d], 1);
        col[p] = src[e];
    }
}

// -------- aggregation (fp16 in/out, fp32 accum), BN fold computed inline --------
template <int F, bool FOLD>
__global__ __launch_bounds__(256) void aggregate_k(const u16* __restrict__ h,
                                                   const int* __restrict__ rowptr,
                                                   const int* __restrict__ col,
                                                   const float* __restrict__ stats,
                                                   const float* __restrict__ gamma,
                                                   const float* __restrict__ beta,
                                                   u16* __restrict__ outp) {
    int node = blockIdx.x * 4 + (threadIdx.x >> 6);
    if (node >= N_NODES) return;
    int lane = threadIdx.x & 63;
    int beg = rowptr[node], end = rowptr[node + 1];
    if constexpr (F == 256) {
        float sc[4], sh[4];
        if constexpr (FOLD) {
            int c4 = lane * 4;
#pragma unroll
            for (int i = 0; i < 4; i++) {
                float mu  = stats[c4 + i] * (1.f / N_NODES);
                float var = stats[HID + c4 + i] * (1.f / N_NODES) - mu * mu;
                float g = gamma[c4 + i] * rsqrtf(var + BN_EPS);
                sc[i] = g;
                sh[i] = beta[c4 + i] - mu * g;
            }
        }
        const u16x4* hp = reinterpret_cast<const u16x4*>(h); // row stride 64
        u16x4 sv = hp[(size_t)node * 64 + lane];
        float acc[4] = {h2f(sv[0]), h2f(sv[1]), h2f(sv[2]), h2f(sv[3])};
        int e = beg;
        for (; e + 4 <= end; e += 4) {
            int s0 = col[e], s1 = col[e + 1], s2 = col[e + 2], s3 = col[e + 3];
            u16x4 v0 = hp[(size_t)s0 * 64 + lane];
            u16x4 v1 = hp[(size_t)s1 * 64 + lane];
            u16x4 v2 = hp[(size_t)s2 * 64 + lane];
            u16x4 v3 = hp[(size_t)s3 * 64 + lane];
#pragma unroll
            for (int i = 0; i < 4; i++)
                acc[i] += (h2f(v0[i]) + h2f(v1[i])) + (h2f(v2[i]) + h2f(v3[i]));
        }
        for (; e < end; ++e) {
            int s = col[e];
            u16x4 v = hp[(size_t)s * 64 + lane];
#pragma unroll
            for (int i = 0; i < 4; i++) acc[i] += h2f(v[i]);
        }
        if constexpr (FOLD) {
            float m = (float)(end - beg + 1);
#pragma unroll
            for (int i = 0; i < 4; i++) acc[i] = acc[i] * sc[i] + m * sh[i];
        }
        u16x4 r;
#pragma unroll
        for (int i = 0; i < 4; i++) r[i] = f2h(acc[i]);
        reinterpret_cast<u16x4*>(outp)[(size_t)node * 64 + lane] = r;
    } else { // F == 128, no fold (layer-1 input)
        const u16x2* hp = reinterpret_cast<const u16x2*>(h); // row stride 64
        u16x2 sv = hp[(size_t)node * 64 + lane];
        float acc[2] = {h2f(sv[0]), h2f(sv[1])};
        int e = beg;
        for (; e + 4 <= end; e += 4) {
            int s0 = col[e], s1 = col[e + 1], s2 = col[e + 2], s3 = col[e + 3];
            u16x2 v0 = hp[(size_t)s0 * 64 + lane];
            u16x2 v1 = hp[(size_t)s1 * 64 + lane];
            u16x2 v2 = hp[(size_t)s2 * 64 + lane];
            u16x2 v3 = hp[(size_t)s3 * 64 + lane];
#pragma unroll
            for (int i = 0; i < 2; i++)
                acc[i] += (h2f(v0[i]) + h2f(v1[i])) + (h2f(v2[i]) + h2f(v3[i]));
        }
        for (; e < end; ++e) {
            int s = col[e];
            u16x2 v = hp[(size_t)s * 64 + lane];
#pragma unroll
            for (int i = 0; i < 2; i++) acc[i] += h2f(v[i]);
        }
        u16x2 r;
        r[0] = f2h(acc[0]); r[1] = f2h(acc[1]);
        reinterpret_cast<u16x2*>(outp)[(size_t)node * 64 + lane] = r;
    }
}

// ------- MFMA GEMM: C[M][256] = fp16(relu(A[M][K] @ W + bias)), A fp16 -------
// Block 128 rows x 256 cols (full row -> in-place safe). 4 waves, each 64x128.
// Staging via global_load_lds: W tile = linear copy of the pre-swizzled image;
// A uses pre-swizzled per-lane global source. 32 MFMA per K-step (1 W plane).
template <int K, bool STATS>
__global__ __launch_bounds__(256, 2) void gemm_mfma(const u16* __restrict__ A,
                                                    const u16* __restrict__ Wth,
                                                    const float* __restrict__ bias,
                                                    u16* __restrict__ C,
                                                    float* __restrict__ stats) {
    constexpr int BM = 128, BK = 32;
    __shared__ alignas(16) u16 Ah[BM * BK];     // 8 KB
    __shared__ alignas(16) u16 Bh[HID * BK];    // 16 KB
    __shared__ float smsum[HID];
    __shared__ float smsq[HID];

    const int tid  = threadIdx.x;
    const int r0   = blockIdx.x * BM;
    const int lane = tid & 63, wv = tid >> 6;
    const int wm = wv >> 1, wn = wv & 1;
    const int l15 = lane & 15, kg = lane >> 4;

    // A staging source precompute (2 chunks/wave, 1KB each):
    // chunk p covers linear LDS units nu = wv*128 + p*64 + lane
    int aro[2], aco[2];
#pragma unroll
    for (int p = 0; p < 2; p++) {
        int nu = wv * 128 + p * 64 + lane;
        int r = nu >> 2, us = nu & 3;
        int u = us ^ ((r >> 1) & 3);
        aro[p] = r;           // row within tile
        aco[p] = u * 8;       // k offset within 32-k step
    }

    f32x4 acc[4][8];
#pragma unroll
    for (int i = 0; i < 4; i++)
#pragma unroll
        for (int j = 0; j < 8; j++) acc[i][j] = (f32x4){0.f, 0.f, 0.f, 0.f};

    for (int k0 = 0; k0 < K; k0 += BK) {
        int t = k0 >> 5;
        // ---- stage A (8 KB): per-lane pre-swizzled source, linear LDS dest ----
#pragma unroll
        for (int p = 0; p < 2; p++) {
            const u16* src = A + (size_t)(r0 + aro[p]) * K + k0 + aco[p];
            gload16(src, (char*)Ah + (size_t)(wv * 2 + p) * 1024);
        }
        // ---- stage W (16 KB): linear image copy, PER-LANE source ----
        const char* wh = (const char*)Wth + (size_t)t * 16384 + (size_t)wv * 4096 + (size_t)lane * 16;
#pragma unroll
        for (int c = 0; c < 4; c++)
            gload16(wh + c * 1024, (char*)Bh + (size_t)wv * 4096 + c * 1024);
        __syncthreads();
        // ---- MFMA: wave tile 64x128, 32 mfma per K-step ----
        f16x8 ah[4];
#pragma unroll
        for (int mi = 0; mi < 4; mi++) {
            int r = wm * 64 + mi * 16 + l15;
            int off = r * 64 + ((kg ^ ((r >> 1) & 3)) << 4);
            ah[mi] = __builtin_bit_cast(f16x8, *reinterpret_cast<const u16x8*>((const char*)Ah + off));
        }
#pragma unroll
        for (int ni = 0; ni < 8; ni++) {
            int n = wn * 128 + ni * 16 + l15;
            int off = n * 64 + ((kg ^ ((n >> 1) & 3)) << 4);
            f16x8 bh = __builtin_bit_cast(f16x8, *reinterpret_cast<const u16x8*>((const char*)Bh + off));
#pragma unroll
            for (int mi = 0; mi < 4; mi++)
                acc[mi][ni] = __builtin_amdgcn_mfma_f32_16x16x32_f16(ah[mi], bh, acc[mi][ni], 0, 0, 0);
        }
        __syncthreads();
    }
    // ---- epilogue: bias + relu + fp16 store; optional per-column stats ----
    if constexpr (STATS) {
        smsum[tid] = 0.f;
        smsq[tid]  = 0.f;
        __syncthreads();
    }
    float bv[8];
#pragma unroll
    for (int ni = 0; ni < 8; ni++) bv[ni] = bias[wn * 128 + ni * 16 + l15];
    float ps[8] = {}, pq[8] = {};
#pragma unroll
    for (int mi = 0; mi < 4; mi++) {
        int rowb = r0 + wm * 64 + mi * 16 + kg * 4;
#pragma unroll
        for (int rr = 0; rr < 4; rr++) {
            int row = rowb + rr;
            if (row < N_NODES) {
                u16* cp = C + (size_t)row * HID + wn * 128 + l15;
#pragma unroll
                for (int ni = 0; ni < 8; ni++) {
                    float v = fmaxf(acc[mi][ni][rr] + bv[ni], 0.f);
                    cp[ni * 16] = f2h(v);
                    if constexpr (STATS) { ps[ni] += v; pq[ni] += v * v; }
                }
            }
        }
    }
    if constexpr (STATS) {
#pragma unroll
        for (int ni = 0; ni < 8; ni++) {
            int c = wn * 128 + ni * 16 + l15;
            atomicAdd(&smsum[c], ps[ni]);
            atomicAdd(&smsq[c], pq[ni]);
        }
        __syncthreads();
        atomicAdd(&stats[tid], smsum[tid]);
        atomicAdd(&stats[HID + tid], smsq[tid]);
    }
}

// ---------------- mean pool (batch sorted), layer-3 BN computed inline ----------------
__device__ __forceinline__ int lowerb(const int* a, int key) {
    int lo = 0, hi = N_NODES;
    while (lo < hi) { int mid = (lo + hi) >> 1; if (a[mid] < key) lo = mid + 1; else hi = mid; }
    return lo;
}

__global__ void pool_k(const u16* __restrict__ h, const int* __restrict__ batch,
                       const float* __restrict__ stats, const float* __restrict__ gamma,
                       const float* __restrict__ beta, float* __restrict__ out) {
    __shared__ int bnd[2];
    int g = blockIdx.x;
    if (threadIdx.x == 0) bnd[0] = lowerb(batch, g);
    if (threadIdx.x == 1) bnd[1] = lowerb(batch, g + 1);
    __syncthreads();
    int lo = bnd[0], hi = bnd[1];
    int c = threadIdx.x;
    float mu  = stats[c] * (1.f / N_NODES);
    float var = stats[HID + c] * (1.f / N_NODES) - mu * mu;
    float sc = gamma[c] * rsqrtf(var + BN_EPS);
    float sh = beta[c] - mu * sc;
    float s = 0.f;
    for (int r = lo; r < hi; ++r) s += h2f(h[(size_t)r * HID + c]);
    int cnt = hi - lo;
    float v = (cnt > 0) ? (sc * (s / (float)cnt) + sh) : 0.f;
    out[(size_t)g * HID + c] = v;
}

// ---------------- launch ----------------
extern "C" void kernel_launch(void* const* d_in, const int* in_sizes, int n_in,
                              void* d_out, int out_size, void* d_ws, size_t ws_size,
                              hipStream_t stream) {
    const float* x   = (const float*)d_in[0];
    const int*   ei  = (const int*)d_in[1];
    const int* batch = (const int*)d_in[2];
    const float* w1a = (const float*)d_in[3];
    const float* b1a = (const float*)d_in[4];
    const float* w2a = (const float*)d_in[5];
    const float* b2a = (const float*)d_in[6];
    const float* ga  = (const float*)d_in[7];
    const float* ba  = (const float*)d_in[8];
    const float* w1s = (const float*)d_in[9];
    const float* b1s = (const float*)d_in[10];
    const float* w2s = (const float*)d_in[11];
    const float* b2s = (const float*)d_in[12];
    const float* gs  = (const float*)d_in[13];
    const float* bs  = (const float*)d_in[14];
    const int* src = ei;
    const int* dst = ei + N_EDGES;

    char* ws = (char*)d_ws;
    size_t off = 0;
    auto alloc = [&](size_t bytes) { void* p = ws + off; off += (bytes + 255) & ~(size_t)255; return p; };
    u16* A      = (u16*)alloc(sizeof(u16) * (size_t)N_NODES * HID);
    u16* B      = (u16*)alloc(sizeof(u16) * (size_t)N_NODES * HID);
    u16* Xb     = (u16*)alloc(sizeof(u16) * (size_t)N_NODES * F_IN);
    int* rowptr = (int*)alloc(sizeof(int) * (N_NODES + 1));
    int* deg    = (int*)alloc(sizeof(int) * N_NODES);
    int* cursor = (int*)alloc(sizeof(int) * N_NODES);
    int* col    = (int*)alloc(sizeof(int) * N_EDGES);
    int* bsum   = (int*)alloc(sizeof(int) * 64);
    float* stats  = (float*)alloc(sizeof(float) * 512 * 3);  // sum||sq per layer
    constexpr size_t WT_TOT = 32768 + 5 * 65536;
    u16* WtH = (u16*)alloc(sizeof(u16) * WT_TOT);
    constexpr size_t o1a = 0, o2a = 32768, o1s0 = 98304, o1s1 = 163840, o2s0 = 229376, o2s1 = 294912;
    float* out    = (float*)d_out;
    (void)ws_size; (void)in_sizes; (void)n_in; (void)out_size;

    // ---- fused prep (x->fp16, W image, zero deg/stats) ----
    prep_k<<<(N_NODES * F_IN / 8 + 255) / 256, 256, 0, stream>>>(
        x, Xb, w1a, w2a, w1s, w2s, WtH, deg, stats);

    // ---- CSR build (by dst) ----
    hist_k<<<N_EDGES / 256, 256, 0, stream>>>(dst, deg);
    scan_part1<<<SCAN_NB, 256, 0, stream>>>(deg, bsum);
    scan_tops<<<1, 64, 0, stream>>>(bsum, rowptr);
    scan_final<<<SCAN_NB, 256, 0, stream>>>(deg, bsum, rowptr, cursor);
    build_csr<<<N_EDGES / 256, 256, 0, stream>>>(src, dst, cursor, col);

    const int AGG_GRID  = (N_NODES + 3) / 4;     // 12500
    const int GEMM_GRID = (N_NODES + 127) / 128; // 391

    // ---- layer 1 ----
    aggregate_k<128, false><<<AGG_GRID, 256, 0, stream>>>(Xb, rowptr, col, nullptr, nullptr, nullptr, A);
    gemm_mfma<128, false><<<GEMM_GRID, 256, 0, stream>>>(A, WtH + o1a, b1a, B, nullptr);
    gemm_mfma<256, true><<<GEMM_GRID, 256, 0, stream>>>(B, WtH + o2a, b2a, B, stats);

    // ---- layer 2 (BN1 folded into aggregate, scale/shift inline) ----
    aggregate_k<256, true><<<AGG_GRID, 256, 0, stream>>>(B, rowptr, col, stats, ga, ba, A);
    gemm_mfma<256, false><<<GEMM_GRID, 256, 0, stream>>>(A, WtH + o1s0, b1s, A, nullptr);
    gemm_mfma<256, true><<<GEMM_GRID, 256, 0, stream>>>(A, WtH + o2s0, b2s, A, stats + 512);

    // ---- layer 3 (BN2 folded into aggregate) ----
    aggregate_k<256, true><<<AGG_GRID, 256, 0, stream>>>(A, rowptr, col, stats + 512, gs, bs, B);
    gemm_mfma<256, false><<<GEMM_GRID, 256, 0, stream>>>(B, WtH + o1s1, b1s + 256, B, nullptr);
    gemm_mfma<256, true><<<GEMM_GRID, 256, 0, stream>>>(B, WtH + o2s1, b2s + 256, B, stats + 1024);

    // ---- pool (BN3 inline) ----
    pool_k<<<N_GRAPHS, 256, 0, stream>>>(B, batch, stats + 1024, gs + 256, bs + 256, out);
}